// Round 2
// baseline (1660.290 us; speedup 1.0000x reference)
//
#include <hip/hip_runtime.h>

#define B_ 8
#define C_ 128
#define F_ 16
#define N_ 512

// ---------------- weight prep: Wsum=W1+W3, Wdiff=W2-W3, WnT = W_node^T ----------------
__global__ __launch_bounds__(256) void k_wprep(
    const float* __restrict__ Wd, const float* __restrict__ Wn,
    float* __restrict__ Wsum, float* __restrict__ Wdiff, float* __restrict__ WnT)
{
    int i = blockIdx.x * 256 + threadIdx.x;          // 0..16383
    int d = i >> 7, c = i & 127;
    const float* row = Wd + (size_t)d * (3 * C_);
    float w1 = row[c];
    float w2 = row[C_ + c];
    float w3 = row[2 * C_ + c];
    Wsum[i]  = w1 + w3;
    Wdiff[i] = w2 - w3;
    // treat i = c2*128 + o : WnT[c2][o] = Wn[o][c2]
    int c2 = i >> 7, o = i & 127;
    WnT[i] = Wn[(size_t)o * C_ + c2];
}

// ---------------- per-(b,yframe) in-degree + zero count ----------------
__global__ __launch_bounds__(256) void k_maskdeg(
    const float* __restrict__ Y, float* __restrict__ deg, int* __restrict__ zc)
{
    int bg = blockIdx.x;            // b*3+g, g in {0,1,2}
    int uc = blockIdx.y;            // u chunk of 32
    int t = threadIdx.x;
    int b = bg / 3, g = bg % 3;
    const float* Yp = Y + ((size_t)b * F_ + g) * N_ * N_;
    int v0 = t, v1 = t + 256;
    float d0 = 0.f, d1 = 0.f;
    int zcount = 0;
    for (int uu = 0; uu < 32; ++uu) {
        int u = uc * 32 + uu;
        float a  = Yp[(size_t)u * N_ + v0];
        float bv = Yp[(size_t)u * N_ + v1];
        zcount += (a == 0.f);
        zcount += (bv == 0.f);
        d0 += (a  != 0.f) ? 1.f : 0.f;
        d1 += (bv != 0.f) ? 1.f : 0.f;
    }
    atomicAdd(&deg[(size_t)bg * N_ + v0], d0);
    atomicAdd(&deg[(size_t)bg * N_ + v1], d1);
    __shared__ int sred[256];
    sred[t] = zcount;
    __syncthreads();
    for (int s = 128; s > 0; s >>= 1) {
        if (t < s) sred[t] += sred[t + s];
        __syncthreads();
    }
    if (t == 0 && sred[0] != 0) atomicAdd(&zc[bg], sred[0]);
}

// ---------------- main: S/D GEMMs, XS=X*S, D store, column sums of XS and X ----------------
#define WCH 132
__global__ __launch_bounds__(256) void k_main(
    const float* __restrict__ infos, const float* __restrict__ Wsum, const float* __restrict__ Wdiff,
    float* __restrict__ XS, float* __restrict__ Dt,
    float* __restrict__ A1row, float* __restrict__ A2row)
{
    __shared__ float Xl[C_ * 64];        // [c][n] 32 KB
    __shared__ float Wls[16 * WCH];      // [cc][d] 8.4 KB
    __shared__ float Wld[16 * WCH];
    int bf = blockIdx.x;
    int b = bf >> 4, f = bf & 15;
    int n0 = blockIdx.y * 64;
    int t = threadIdx.x;
    {
        const float* base = infos + (((size_t)b * C_) * F_ + f) * N_ + n0;
        for (int i = t; i < C_ * 64; i += 256) {
            int c = i >> 6, n2 = i & 63;
            Xl[c * 64 + n2] = base[(size_t)c * F_ * N_ + n2];
        }
    }
    int tx = t & 31;     // d = tx*4 + j
    int ty = t >> 5;     // n = n0 + ty*8 + i
    float acc_s[8][4];
    float acc_d[8][4];
    #pragma unroll
    for (int i = 0; i < 8; ++i)
        #pragma unroll
        for (int j = 0; j < 4; ++j) { acc_s[i][j] = 0.f; acc_d[i][j] = 0.f; }

    for (int c0 = 0; c0 < C_; c0 += 16) {
        __syncthreads();
        for (int i = t; i < 16 * C_; i += 256) {
            int d = i >> 4, cc = i & 15;
            Wls[cc * WCH + d] = Wsum[(size_t)d * C_ + c0 + cc];
            Wld[cc * WCH + d] = Wdiff[(size_t)d * C_ + c0 + cc];
        }
        __syncthreads();
        #pragma unroll
        for (int cc = 0; cc < 16; ++cc) {
            int c = c0 + cc;
            const float4 x0  = *reinterpret_cast<const float4*>(&Xl[c * 64 + ty * 8]);
            const float4 x1  = *reinterpret_cast<const float4*>(&Xl[c * 64 + ty * 8 + 4]);
            const float4 wsv = *reinterpret_cast<const float4*>(&Wls[cc * WCH + tx * 4]);
            const float4 wdv = *reinterpret_cast<const float4*>(&Wld[cc * WCH + tx * 4]);
            float xs_[8] = {x0.x, x0.y, x0.z, x0.w, x1.x, x1.y, x1.z, x1.w};
            #pragma unroll
            for (int i = 0; i < 8; ++i) {
                acc_s[i][0] += xs_[i] * wsv.x;
                acc_s[i][1] += xs_[i] * wsv.y;
                acc_s[i][2] += xs_[i] * wsv.z;
                acc_s[i][3] += xs_[i] * wsv.w;
                acc_d[i][0] += xs_[i] * wdv.x;
                acc_d[i][1] += xs_[i] * wdv.y;
                acc_d[i][2] += xs_[i] * wdv.z;
                acc_d[i][3] += xs_[i] * wdv.w;
            }
        }
    }
    // epilogue: stores + per-block column-sum partials
    float psA[4] = {0.f, 0.f, 0.f, 0.f};
    float psB[4] = {0.f, 0.f, 0.f, 0.f};
    #pragma unroll
    for (int i = 0; i < 8; ++i) {
        int nl = ty * 8 + i;
        int n = n0 + nl;
        float xv0 = Xl[(tx * 4 + 0) * 64 + nl];
        float xv1 = Xl[(tx * 4 + 1) * 64 + nl];
        float xv2 = Xl[(tx * 4 + 2) * 64 + nl];
        float xv3 = Xl[(tx * 4 + 3) * 64 + nl];
        float4 xsv = make_float4(xv0 * acc_s[i][0], xv1 * acc_s[i][1], xv2 * acc_s[i][2], xv3 * acc_s[i][3]);
        float4 dtv = make_float4(acc_d[i][0], acc_d[i][1], acc_d[i][2], acc_d[i][3]);
        size_t off = (((size_t)bf * N_) + n) * C_ + tx * 4;
        *reinterpret_cast<float4*>(&XS[off]) = xsv;
        *reinterpret_cast<float4*>(&Dt[off]) = dtv;
        psA[0] += xsv.x; psA[1] += xsv.y; psA[2] += xsv.z; psA[3] += xsv.w;
        psB[0] += xv0;   psB[1] += xv1;   psB[2] += xv2;   psB[3] += xv3;
    }
    __syncthreads();
    float* redA = Wls;   // reuse (>= 1024 floats each)
    float* redB = Wld;
    *reinterpret_cast<float4*>(&redA[((size_t)ty * 32 + tx) * 4]) = make_float4(psA[0], psA[1], psA[2], psA[3]);
    *reinterpret_cast<float4*>(&redB[((size_t)ty * 32 + tx) * 4]) = make_float4(psB[0], psB[1], psB[2], psB[3]);
    __syncthreads();
    if (t < C_) {
        float sA = 0.f, sB = 0.f;
        #pragma unroll
        for (int gy = 0; gy < 8; ++gy) {
            sA += redA[gy * C_ + t];
            sB += redB[gy * C_ + t];
        }
        atomicAdd(&A1row[(size_t)bf * C_ + t], sA);
        atomicAdd(&A2row[(size_t)bf * C_ + t], sB);
    }
}

// ---------------- dense fallback (only if some mask entry is zero) ----------------
__global__ __launch_bounds__(128) void k_fallback(
    const float* __restrict__ Y, const float* __restrict__ infos,
    const float* __restrict__ XS, const float* __restrict__ Dt,
    const float* __restrict__ deg, const int* __restrict__ zc,
    const float* __restrict__ bd, const float* __restrict__ Wn, const float* __restrict__ bn,
    float* __restrict__ out)
{
    int bf = blockIdx.x;
    int b = bf >> 4, f = bf & 15;
    int g = (f == 0) ? 0 : ((f <= 11) ? 1 : 2);
    if (zc[b * 3 + g] == 0) return;    // fast path handled elsewhere
    __shared__ float aggL[C_];
    int t = threadIdx.x;
    const float* Yp = Y + ((size_t)b * F_ + g) * N_ * N_;
    for (int vi = 0; vi < 8; ++vi) {
        int v = blockIdx.y * 8 + vi;
        float acc1 = 0.f, acc2 = 0.f;
        const float* XSp = XS + ((size_t)bf * N_) * C_ + t;
        const float* Xp  = infos + (((size_t)b * C_ + t) * F_ + f) * N_;
        for (int u = 0; u < N_; ++u) {
            float m = (Yp[(size_t)u * N_ + v] != 0.f) ? 1.f : 0.f;
            acc1 += m * XSp[(size_t)u * C_];
            acc2 += m * Xp[u];
        }
        float dgv = fmaxf(deg[((size_t)b * 3 + g) * N_ + v], 1.f);
        float aggv = (acc1 + acc2 * (Dt[(((size_t)bf * N_) + v) * C_ + t] + bd[t])) / dgv;
        aggL[t] = aggv;
        __syncthreads();
        float h = bn[t];
        for (int c2 = 0; c2 < C_; ++c2) h += aggL[c2] * Wn[(size_t)t * C_ + c2];
        h = fmaxf(h, 0.f);
        out[(((size_t)b * C_ + t) * F_ + f) * N_ + v] = h;
        __syncthreads();
    }
}

// ---------------- fast-path epilogue: agg + 128x128 projection + transpose-store ----------------
#define AGS 132
__global__ __launch_bounds__(256) void k_epilogue(
    const float* __restrict__ A1row, const float* __restrict__ A2row,
    const float* __restrict__ Dt, const float* __restrict__ deg, const int* __restrict__ zc,
    const float* __restrict__ bd, const float* __restrict__ WnT, const float* __restrict__ bn,
    float* __restrict__ out)
{
    int bf = blockIdx.x;
    int b = bf >> 4, f = bf & 15;
    int g = (f == 0) ? 0 : ((f <= 11) ? 1 : 2);
    if (zc[b * 3 + g] != 0) return;    // dense fallback handles this (b,g)
    __shared__ float Whalf[C_ * 64];   // [c][oo]  32 KB
    __shared__ float aggS[32 * AGS];   // [vloc][c] 16.9 KB
    int t = threadIdx.x;
    int v0 = blockIdx.y * 64;
    int cph = t & 127;                 // phase-1 channel
    int vh  = t >> 7;                  // phase-1 v-half
    float ra1 = A1row[(size_t)bf * C_ + cph];
    float ra2 = A2row[(size_t)bf * C_ + cph];
    float rbd = bd[cph];
    int og = ((t >> 3) & 15) * 4;      // phase-2: 4 consecutive o within o-half
    int vq = (t & 7) | ((t >> 7) << 3);// phase-2: 0..15 -> v pair
    const float* degp = deg + ((size_t)b * 3 + g) * N_;

    for (int vs = 0; vs < 2; ++vs) {
        __syncthreads();
        // phase 1: agg for 32 v into LDS
        #pragma unroll
        for (int j = 0; j < 16; ++j) {
            int vloc = vh * 16 + j;
            int vg = v0 + vs * 32 + vloc;
            float dd  = Dt[(((size_t)bf * N_) + vg) * C_ + cph];
            float dgv = fmaxf(degp[vg], 1.f);
            aggS[vloc * AGS + cph] = (ra1 + ra2 * (dd + rbd)) / dgv;
        }
        for (int oh = 0; oh < 2; ++oh) {
            __syncthreads();
            for (int i = t; i < C_ * 64; i += 256) {
                int c = i >> 6, oo = i & 63;
                Whalf[i] = WnT[(size_t)c * C_ + oh * 64 + oo];
            }
            __syncthreads();
            float acc00 = 0.f, acc01 = 0.f, acc02 = 0.f, acc03 = 0.f;
            float acc10 = 0.f, acc11 = 0.f, acc12 = 0.f, acc13 = 0.f;
            const float* aggp0 = &aggS[(vq * 2 + 0) * AGS];
            const float* aggp1 = &aggS[(vq * 2 + 1) * AGS];
            #pragma unroll 4
            for (int c = 0; c < C_; ++c) {
                const float4 wv = *reinterpret_cast<const float4*>(&Whalf[c * 64 + og]);
                float a0 = aggp0[c];
                float a1 = aggp1[c];
                acc00 += a0 * wv.x; acc01 += a0 * wv.y; acc02 += a0 * wv.z; acc03 += a0 * wv.w;
                acc10 += a1 * wv.x; acc11 += a1 * wv.y; acc12 += a1 * wv.z; acc13 += a1 * wv.w;
            }
            int vbase = v0 + vs * 32 + vq * 2;
            int obase = oh * 64 + og;
            size_t ostride = (size_t)F_ * N_;
            size_t ooff = (((size_t)b * C_ + obase) * F_ + f) * N_ + vbase;
            float bn0 = bn[obase + 0], bn1 = bn[obase + 1], bn2 = bn[obase + 2], bn3 = bn[obase + 3];
            float2 s0 = make_float2(fmaxf(acc00 + bn0, 0.f), fmaxf(acc10 + bn0, 0.f));
            float2 s1 = make_float2(fmaxf(acc01 + bn1, 0.f), fmaxf(acc11 + bn1, 0.f));
            float2 s2 = make_float2(fmaxf(acc02 + bn2, 0.f), fmaxf(acc12 + bn2, 0.f));
            float2 s3 = make_float2(fmaxf(acc03 + bn3, 0.f), fmaxf(acc13 + bn3, 0.f));
            *reinterpret_cast<float2*>(&out[ooff + 0 * ostride]) = s0;
            *reinterpret_cast<float2*>(&out[ooff + 1 * ostride]) = s1;
            *reinterpret_cast<float2*>(&out[ooff + 2 * ostride]) = s2;
            *reinterpret_cast<float2*>(&out[ooff + 3 * ostride]) = s3;
        }
    }
}

extern "C" void kernel_launch(void* const* d_in, const int* in_sizes, int n_in,
                              void* d_out, int out_size, void* d_ws, size_t ws_size,
                              hipStream_t stream)
{
    const float* Y     = (const float*)d_in[0];
    const float* infos = (const float*)d_in[1];
    const float* Wd    = (const float*)d_in[2];
    const float* bd    = (const float*)d_in[3];
    const float* Wn    = (const float*)d_in[4];
    const float* bn    = (const float*)d_in[5];
    float* out = (float*)d_out;
    float* ws  = (float*)d_ws;

    float* deg   = ws;                        // 24*512 = 12288 floats
    int*   zc    = (int*)(ws + 12288);        // 24 ints (padded to 32)
    float* A1row = ws + 12288 + 32;           // B*F*C = 16384
    float* A2row = A1row + 16384;
    float* Wsum  = A2row + 16384;             // 16384
    float* Wdiff = Wsum + 16384;              // 16384
    float* WnT   = Wdiff + 16384;             // 16384
    float* XS    = WnT + 16384;               // 8388608
    float* Dt    = XS + (size_t)8388608;      // 8388608  -> total ~64.4 MB

    hipMemsetAsync(d_ws, 0, (size_t)(12288 + 32 + 2 * 16384) * sizeof(float), stream);
    k_wprep<<<64, 256, 0, stream>>>(Wd, Wn, Wsum, Wdiff, WnT);
    k_maskdeg<<<dim3(24, 16), 256, 0, stream>>>(Y, deg, zc);
    k_main<<<dim3(B_ * F_, 8), 256, 0, stream>>>(infos, Wsum, Wdiff, XS, Dt, A1row, A2row);
    k_fallback<<<dim3(B_ * F_, 64), 128, 0, stream>>>(Y, infos, XS, Dt, deg, zc, bd, Wn, bn, out);
    k_epilogue<<<dim3(B_ * F_, 8), 256, 0, stream>>>(A1row, A2row, Dt, deg, zc, bd, WnT, bn, out);
}

// Round 3
// 356.806 us; speedup vs baseline: 4.6532x; 4.6532x over previous
//
#include <hip/hip_runtime.h>

#define B_ 8
#define C_ 128
#define F_ 16
#define N_ 512
#define CAP_ (N_ * N_)   // zero-edge list capacity per (b,g) — cannot overflow

// ---------------- weight prep: Wsum=W1+W3, Wdiff=W2-W3, WnT = W_node^T ----------------
__global__ __launch_bounds__(256) void k_wprep(
    const float* __restrict__ Wd, const float* __restrict__ Wn,
    float* __restrict__ Wsum, float* __restrict__ Wdiff, float* __restrict__ WnT)
{
    int i = blockIdx.x * 256 + threadIdx.x;          // 0..16383
    int d = i >> 7, c = i & 127;
    const float* row = Wd + (size_t)d * (3 * C_);
    float w1 = row[c];
    float w2 = row[C_ + c];
    float w3 = row[2 * C_ + c];
    Wsum[i]  = w1 + w3;
    Wdiff[i] = w2 - w3;
    int c2 = i >> 7, o = i & 127;
    WnT[i] = Wn[(size_t)o * C_ + c2];
}

// ---------------- per-(b,yframe) in-degree + zero-edge list ----------------
__global__ __launch_bounds__(256) void k_maskdeg(
    const float* __restrict__ Y, float* __restrict__ deg,
    int* __restrict__ cnt, int* __restrict__ list)
{
    int bg = blockIdx.x;            // b*3+g
    int uc = blockIdx.y;            // u chunk of 32
    int t = threadIdx.x;
    int b = bg / 3, g = bg % 3;
    const float* Yp = Y + ((size_t)b * F_ + g) * N_ * N_;
    float d0 = 0.f, d1 = 0.f;
    for (int uu = 0; uu < 32; ++uu) {
        int u = uc * 32 + uu;
        float a  = Yp[(size_t)u * N_ + t];
        float bv = Yp[(size_t)u * N_ + t + 256];
        if (a == 0.f) {
            int idx = atomicAdd(&cnt[bg], 1);
            list[(size_t)bg * CAP_ + idx] = (u << 9) | t;
        } else d0 += 1.f;
        if (bv == 0.f) {
            int idx = atomicAdd(&cnt[bg], 1);
            list[(size_t)bg * CAP_ + idx] = (u << 9) | (t + 256);
        } else d1 += 1.f;
    }
    atomicAdd(&deg[(size_t)bg * N_ + t], d0);
    atomicAdd(&deg[(size_t)bg * N_ + t + 256], d1);
}

// ---------------- colsum pass: A1[c]=sum_u X[u,c]*S[u,c], A2[c]=sum_u X[u,c] ----------------
#define WCH 132
__global__ __launch_bounds__(256) void k_colsum(
    const float* __restrict__ infos, const float* __restrict__ Wsum,
    float* __restrict__ A1row, float* __restrict__ A2row)
{
    __shared__ float Xl[C_ * 64];        // [c][n] 32 KB
    __shared__ float Wls[16 * WCH];      // [cc][d] 8.4 KB (also reused for reduction)
    int bf = blockIdx.x;
    int b = bf >> 4, f = bf & 15;
    int n0 = blockIdx.y * 64;
    int t = threadIdx.x;
    {
        const float* base = infos + (((size_t)b * C_) * F_ + f) * N_ + n0;
        for (int i = t; i < C_ * 64; i += 256) {
            int c = i >> 6, n2 = i & 63;
            Xl[c * 64 + n2] = base[(size_t)c * F_ * N_ + n2];
        }
    }
    int tx = t & 31;     // d = tx*4 + j
    int ty = t >> 5;     // n = n0 + ty*8 + i
    float acc_s[8][4];
    #pragma unroll
    for (int i = 0; i < 8; ++i)
        #pragma unroll
        for (int j = 0; j < 4; ++j) acc_s[i][j] = 0.f;

    for (int c0 = 0; c0 < C_; c0 += 16) {
        __syncthreads();
        for (int i = t; i < 16 * C_; i += 256) {
            int d = i >> 4, cc = i & 15;
            Wls[cc * WCH + d] = Wsum[(size_t)d * C_ + c0 + cc];
        }
        __syncthreads();
        #pragma unroll
        for (int cc = 0; cc < 16; ++cc) {
            int c = c0 + cc;
            const float4 x0  = *reinterpret_cast<const float4*>(&Xl[c * 64 + ty * 8]);
            const float4 x1  = *reinterpret_cast<const float4*>(&Xl[c * 64 + ty * 8 + 4]);
            const float4 wsv = *reinterpret_cast<const float4*>(&Wls[cc * WCH + tx * 4]);
            float xs_[8] = {x0.x, x0.y, x0.z, x0.w, x1.x, x1.y, x1.z, x1.w};
            #pragma unroll
            for (int i = 0; i < 8; ++i) {
                acc_s[i][0] += xs_[i] * wsv.x;
                acc_s[i][1] += xs_[i] * wsv.y;
                acc_s[i][2] += xs_[i] * wsv.z;
                acc_s[i][3] += xs_[i] * wsv.w;
            }
        }
    }
    // per-thread partial column sums
    float psA[4] = {0.f, 0.f, 0.f, 0.f};
    float psB[4] = {0.f, 0.f, 0.f, 0.f};
    #pragma unroll
    for (int i = 0; i < 8; ++i) {
        int nl = ty * 8 + i;
        float xv0 = Xl[(tx * 4 + 0) * 64 + nl];
        float xv1 = Xl[(tx * 4 + 1) * 64 + nl];
        float xv2 = Xl[(tx * 4 + 2) * 64 + nl];
        float xv3 = Xl[(tx * 4 + 3) * 64 + nl];
        psA[0] += xv0 * acc_s[i][0];
        psA[1] += xv1 * acc_s[i][1];
        psA[2] += xv2 * acc_s[i][2];
        psA[3] += xv3 * acc_s[i][3];
        psB[0] += xv0; psB[1] += xv1; psB[2] += xv2; psB[3] += xv3;
    }
    __syncthreads();
    float* redA = Wls;            // 1024 floats
    float* redB = Wls + 1024;     // 1024 floats (Wls has 2112)
    *reinterpret_cast<float4*>(&redA[((size_t)ty * 32 + tx) * 4]) = make_float4(psA[0], psA[1], psA[2], psA[3]);
    *reinterpret_cast<float4*>(&redB[((size_t)ty * 32 + tx) * 4]) = make_float4(psB[0], psB[1], psB[2], psB[3]);
    __syncthreads();
    if (t < C_) {
        float sA = 0.f, sB = 0.f;
        #pragma unroll
        for (int gy = 0; gy < 8; ++gy) {
            sA += redA[gy * C_ + t];
            sB += redB[gy * C_ + t];
        }
        atomicAdd(&A1row[(size_t)bf * C_ + t], sA);
        atomicAdd(&A2row[(size_t)bf * C_ + t], sB);
    }
}

// ---------------- Meff[bf] = (Wn . diag(A2)) * Wdiff ; c0[bf] = Wn*(A1 + A2.*bd) ----------------
#define UP 68
#define VP 132
__global__ __launch_bounds__(256) void k_meff(
    const float* __restrict__ A1row, const float* __restrict__ A2row,
    const float* __restrict__ WnT, const float* __restrict__ Wdiff,
    const float* __restrict__ bd,
    float* __restrict__ Meff, float* __restrict__ c0all)
{
    __shared__ float U[16 * UP];    // [cc][o-half 64]   (Wn^T row * A2)
    __shared__ float V[16 * VP];    // [cc][c 128]       (Wdiff row)
    __shared__ float A2l[C_], El[C_];
    int bf = blockIdx.x, oh = blockIdx.y, t = threadIdx.x;
    if (t < C_) {
        float a1 = A1row[(size_t)bf * C_ + t];
        float a2 = A2row[(size_t)bf * C_ + t];
        A2l[t] = a2;
        El[t] = a1 + a2 * bd[t];
    }
    __syncthreads();
    int tx = t & 31;              // c = tx*4 + j
    int ty = t >> 5;              // o = oh*64 + ty*8 + i
    float acc[8][4];
    #pragma unroll
    for (int i = 0; i < 8; ++i)
        #pragma unroll
        for (int j = 0; j < 4; ++j) acc[i][j] = 0.f;

    for (int cp0 = 0; cp0 < C_; cp0 += 16) {
        __syncthreads();
        for (int i = t; i < 16 * 64; i += 256) {
            int cc = i >> 6, oo = i & 63;
            U[cc * UP + oo] = WnT[(size_t)(cp0 + cc) * C_ + oh * 64 + oo] * A2l[cp0 + cc];
        }
        for (int i = t; i < 16 * C_; i += 256) {
            int cc = i >> 7, c = i & 127;
            V[cc * VP + c] = Wdiff[(size_t)(cp0 + cc) * C_ + c];
        }
        __syncthreads();
        #pragma unroll
        for (int cc = 0; cc < 16; ++cc) {
            const float4 u0 = *reinterpret_cast<const float4*>(&U[cc * UP + ty * 8]);
            const float4 u1 = *reinterpret_cast<const float4*>(&U[cc * UP + ty * 8 + 4]);
            const float4 vv = *reinterpret_cast<const float4*>(&V[cc * VP + tx * 4]);
            float uu[8] = {u0.x, u0.y, u0.z, u0.w, u1.x, u1.y, u1.z, u1.w};
            #pragma unroll
            for (int i = 0; i < 8; ++i) {
                acc[i][0] += uu[i] * vv.x;
                acc[i][1] += uu[i] * vv.y;
                acc[i][2] += uu[i] * vv.z;
                acc[i][3] += uu[i] * vv.w;
            }
        }
    }
    #pragma unroll
    for (int i = 0; i < 8; ++i) {
        int o = oh * 64 + ty * 8 + i;
        *reinterpret_cast<float4*>(&Meff[((size_t)bf * C_ + o) * C_ + tx * 4]) =
            make_float4(acc[i][0], acc[i][1], acc[i][2], acc[i][3]);
    }
    __syncthreads();
    if (t < 64) {
        int o = oh * 64 + t;
        float s = 0.f;
        for (int c = 0; c < C_; ++c) s += WnT[(size_t)c * C_ + o] * El[c];
        c0all[(size_t)bf * C_ + o] = s;
    }
}

// ---------------- final: h[o,v] = relu((c0[o] + Meff*X[v] - corrections)/deg[v] + bn[o]) ----------------
__global__ __launch_bounds__(256) void k_final(
    const float* __restrict__ infos, const float* __restrict__ Meff,
    const float* __restrict__ c0all, const float* __restrict__ deg,
    const int* __restrict__ cnt, const int* __restrict__ list,
    const float* __restrict__ Wsum, const float* __restrict__ Wdiff,
    const float* __restrict__ Wn, const float* __restrict__ bd, const float* __restrict__ bn,
    float* __restrict__ out)
{
    __shared__ float Xl[C_ * 64];      // [c][v] 32KB
    __shared__ float Ml[16 * 132];     // [cc][o] 8.4KB
    __shared__ float Xu[C_], NC[C_];
    int bf = blockIdx.x;
    int b = bf >> 4, f = bf & 15;
    int g = (f == 0) ? 0 : ((f <= 11) ? 1 : 2);
    int v0 = blockIdx.y * 64;
    int t = threadIdx.x;
    {
        const float* base = infos + (((size_t)b * C_) * F_ + f) * N_ + v0;
        for (int i = t; i < C_ * 64; i += 256) {
            int c = i >> 6, n2 = i & 63;
            Xl[c * 64 + n2] = base[(size_t)c * F_ * N_ + n2];
        }
    }
    int tx = t & 15;          // v = v0 + tx*4 + j
    int ty = t >> 4;          // o = ty*8 + i
    float acc[8][4];          // [o][v]
    #pragma unroll
    for (int i = 0; i < 8; ++i)
        #pragma unroll
        for (int j = 0; j < 4; ++j) acc[i][j] = 0.f;

    for (int c0 = 0; c0 < C_; c0 += 16) {
        __syncthreads();
        for (int i = t; i < 16 * C_; i += 256) {
            int cc = i & 15, o = i >> 4;
            Ml[cc * 132 + o] = Meff[((size_t)bf * C_ + o) * C_ + c0 + cc];
        }
        __syncthreads();
        #pragma unroll
        for (int cc = 0; cc < 16; ++cc) {
            const float4 m0 = *reinterpret_cast<const float4*>(&Ml[cc * 132 + ty * 8]);
            const float4 m1 = *reinterpret_cast<const float4*>(&Ml[cc * 132 + ty * 8 + 4]);
            const float4 xv = *reinterpret_cast<const float4*>(&Xl[(c0 + cc) * 64 + tx * 4]);
            float mm[8] = {m0.x, m0.y, m0.z, m0.w, m1.x, m1.y, m1.z, m1.w};
            #pragma unroll
            for (int i = 0; i < 8; ++i) {
                acc[i][0] += mm[i] * xv.x;
                acc[i][1] += mm[i] * xv.y;
                acc[i][2] += mm[i] * xv.z;
                acc[i][3] += mm[i] * xv.w;
            }
        }
    }
    // ---- sparse zero-edge corrections (rare; block-uniform control flow) ----
    int bg = b * 3 + g;
    int nz = cnt[bg];
    for (int e = 0; e < nz; ++e) {
        int p = list[(size_t)bg * CAP_ + e];
        int u = p >> 9, v = p & 511;
        if ((v >> 6) != (int)blockIdx.y) continue;
        int vl = v - v0;
        __syncthreads();
        if (t < C_) Xu[t] = infos[(((size_t)b * C_ + t) * F_ + f) * N_ + u];
        __syncthreads();
        if (t < C_) {
            float s = 0.f, dv = 0.f;
            const float* wsr = Wsum + (size_t)t * C_;
            const float* wdr = Wdiff + (size_t)t * C_;
            for (int c = 0; c < C_; ++c) {
                s  += wsr[c] * Xu[c];
                dv += wdr[c] * Xl[c * 64 + vl];
            }
            NC[t] = Xu[t] * (s + dv + bd[t]);   // XS[u] + X[u].*(D[v]+bd)
        }
        __syncthreads();
        if (tx == (vl >> 2)) {
            int j = vl & 3;
            #pragma unroll
            for (int i = 0; i < 8; ++i) {
                int o = ty * 8 + i;
                float s = 0.f;
                const float* wnr = Wn + (size_t)o * C_;
                for (int c = 0; c < C_; ++c) s += wnr[c] * NC[c];
                acc[i][j] -= s;
            }
        }
        __syncthreads();
    }
    // ---- epilogue: /deg, +bias, relu, store [B,O,F,N] ----
    const float* degp = deg + (size_t)bg * N_;
    const float4 dgv = *reinterpret_cast<const float4*>(&degp[v0 + tx * 4]);
    float dg0 = fmaxf(dgv.x, 1.f), dg1 = fmaxf(dgv.y, 1.f);
    float dg2 = fmaxf(dgv.z, 1.f), dg3 = fmaxf(dgv.w, 1.f);
    #pragma unroll
    for (int i = 0; i < 8; ++i) {
        int o = ty * 8 + i;
        float c0v = c0all[(size_t)bf * C_ + o];
        float bnv = bn[o];
        float4 r;
        r.x = fmaxf((acc[i][0] + c0v) / dg0 + bnv, 0.f);
        r.y = fmaxf((acc[i][1] + c0v) / dg1 + bnv, 0.f);
        r.z = fmaxf((acc[i][2] + c0v) / dg2 + bnv, 0.f);
        r.w = fmaxf((acc[i][3] + c0v) / dg3 + bnv, 0.f);
        *reinterpret_cast<float4*>(&out[(((size_t)b * C_ + o) * F_ + f) * N_ + v0 + tx * 4]) = r;
    }
}

extern "C" void kernel_launch(void* const* d_in, const int* in_sizes, int n_in,
                              void* d_out, int out_size, void* d_ws, size_t ws_size,
                              hipStream_t stream)
{
    const float* Y     = (const float*)d_in[0];
    const float* infos = (const float*)d_in[1];
    const float* Wd    = (const float*)d_in[2];
    const float* bd    = (const float*)d_in[3];
    const float* Wn    = (const float*)d_in[4];
    const float* bn    = (const float*)d_in[5];
    float* out = (float*)d_out;
    float* ws  = (float*)d_ws;

    float* deg   = ws;                        // 12288 floats
    int*   cnt   = (int*)(ws + 12288);        // 32 ints
    float* A1row = ws + 12288 + 32;           // 16384
    float* A2row = A1row + 16384;             // 16384
    float* Wsum  = A2row + 16384;             // 16384
    float* Wdiff = Wsum + 16384;              // 16384
    float* WnT   = Wdiff + 16384;             // 16384
    float* c0all = WnT + 16384;               // 16384
    float* Meff  = c0all + 16384;             // 128*128*128 = 2097152
    int*   list  = (int*)(Meff + 2097152);    // 24*CAP_ ints (~25 MB)

    // zero: deg, cnt, A1row, A2row (contiguous prefix)
    hipMemsetAsync(d_ws, 0, (size_t)(12288 + 32 + 2 * 16384) * sizeof(float), stream);
    k_wprep<<<64, 256, 0, stream>>>(Wd, Wn, Wsum, Wdiff, WnT);
    k_maskdeg<<<dim3(24, 16), 256, 0, stream>>>(Y, deg, cnt, list);
    k_colsum<<<dim3(B_ * F_, 8), 256, 0, stream>>>(infos, Wsum, A1row, A2row);
    k_meff<<<dim3(B_ * F_, 2), 256, 0, stream>>>(A1row, A2row, WnT, Wdiff, bd, Meff, c0all);
    k_final<<<dim3(B_ * F_, 8), 256, 0, stream>>>(infos, Meff, c0all, deg, cnt, list,
                                                  Wsum, Wdiff, Wn, bd, bn, out);
}

// Round 4
// 299.496 us; speedup vs baseline: 5.5436x; 1.1914x over previous
//
#include <hip/hip_runtime.h>

#define B_ 8
#define C_ 128
#define F_ 16
#define N_ 512
#define CAP_ (N_ * N_)

typedef __attribute__((ext_vector_type(8))) short bf16x8;
typedef __attribute__((ext_vector_type(4))) float f32x4;

#define MFMA(a, b, c) __builtin_amdgcn_mfma_f32_16x16x32_bf16((a), (b), (c), 0, 0, 0)
#define SWZ(x) ((x) ^ ((((x) >> 8) & 7) << 4))

__device__ __forceinline__ ushort f2bf(float x) {
    unsigned u = __float_as_uint(x);
    u += 0x7fffu + ((u >> 16) & 1u);
    return (ushort)(u >> 16);
}

// ---------------- weight prep ----------------
__global__ __launch_bounds__(256) void k_wprep(
    const float* __restrict__ Wd, const float* __restrict__ Wn,
    float* __restrict__ Wsum, float* __restrict__ Wdiff, float* __restrict__ WsumT,
    ushort* __restrict__ WdT_bf, float* __restrict__ WnT)
{
    int i = blockIdx.x * 256 + threadIdx.x;          // 0..16383
    int d = i >> 7, c = i & 127;
    const float* row = Wd + (size_t)d * (3 * C_);
    float w1 = row[c], w2 = row[C_ + c], w3 = row[2 * C_ + c];
    float ws = w1 + w3, wdf = w2 - w3;
    Wsum[i] = ws;
    Wdiff[i] = wdf;
    WsumT[(size_t)c * C_ + d] = ws;
    WdT_bf[(size_t)c * C_ + d] = f2bf(wdf);
    WnT[i] = Wn[(size_t)(i & 127) * C_ + (i >> 7)];  // WnT[c2][o] = Wn[o][c2]
}

// ---------------- degree + zero-edge list ----------------
__global__ __launch_bounds__(256) void k_deg(
    const float* __restrict__ Y, float* __restrict__ deg,
    int* __restrict__ cnt, int* __restrict__ list)
{
    __shared__ float red[256];
    int bg = blockIdx.x, vc = blockIdx.y, t = threadIdx.x;
    int b = bg / 3, g = bg % 3;
    int vl = t & 31, q = t >> 5;          // q in 0..7, u-segment of 64
    int v = vc * 32 + vl;
    const float* Yp = Y + ((size_t)b * F_ + g) * N_ * N_ + v;
    float dsum = 0.f;
    #pragma unroll 4
    for (int i = 0; i < 64; ++i) {
        int u = q * 64 + i;
        float a = Yp[(size_t)u * N_];
        if (a == 0.f) {
            int idx = atomicAdd(&cnt[bg], 1);
            list[(size_t)bg * CAP_ + idx] = (u << 9) | v;
        } else dsum += 1.f;
    }
    red[t] = dsum;
    __syncthreads();
    if (t < 32) {
        float s = 0.f;
        #pragma unroll
        for (int qq = 0; qq < 8; ++qq) s += red[qq * 32 + t];
        deg[(size_t)bg * N_ + vc * 32 + t] = s;
    }
}

// ---------------- Gram: G=X^T X via MFMA; A1=diag(Wsum*G); A2=colsum(X) ----------------
__global__ __launch_bounds__(256) void k_gram(
    const float* __restrict__ infos, const float* __restrict__ WsumT,
    float* __restrict__ A1row, float* __restrict__ A2row)
{
    __shared__ float smf[8448];           // union: Xs dbuf (2x128x40 shorts = 5120 f) / Gl 128x66 f32
    __shared__ float red[256];
    short* Xs = (short*)smf;
    float* Gl = smf;
    int bf = blockIdx.x, nh = blockIdx.y, t = threadIdx.x;
    int b = bf >> 4, f = bf & 15;
    const float* Xg = infos + ((size_t)b * C_ * F_ + f) * N_;   // row c at +c*F_*N_

    float a2p0 = 0.f, a2p1 = 0.f, a2p2 = 0.f, a2p3 = 0.f;

    auto STAGE = [&](int buf, int ks) {
        int u0 = ks * 32;
        #pragma unroll
        for (int it = 0; it < 4; ++it) {
            int idx = it * 256 + t;                 // 0..1023
            int c = idx >> 3, uq = idx & 7;
            const float4 x = *(const float4*)(Xg + (size_t)c * (F_ * N_) + u0 + uq * 4);
            float s4 = x.x + x.y + x.z + x.w;
            if (it == 0) a2p0 += s4; else if (it == 1) a2p1 += s4;
            else if (it == 2) a2p2 += s4; else a2p3 += s4;
            short4 h;
            h.x = (short)f2bf(x.x); h.y = (short)f2bf(x.y);
            h.z = (short)f2bf(x.z); h.w = (short)f2bf(x.w);
            *(short4*)&Xs[buf * 5120 + c * 40 + uq * 4] = h;
        }
    };

    int l = t & 63, w = t >> 6;
    int r = l & 15, q = l >> 4;
    f32x4 acc[2][4];
    #pragma unroll
    for (int mi = 0; mi < 2; ++mi)
        #pragma unroll
        for (int ni = 0; ni < 4; ++ni) acc[mi][ni] = (f32x4){0.f, 0.f, 0.f, 0.f};

    STAGE(0, 0);
    for (int ks = 0; ks < 16; ++ks) {
        __syncthreads();
        if (ks < 15) STAGE((ks + 1) & 1, ks + 1);
        const short* Xb = &Xs[(ks & 1) * 5120];
        bf16x8 a0 = *(const bf16x8*)&Xb[(w * 32 + r) * 40 + q * 8];
        bf16x8 a1 = *(const bf16x8*)&Xb[(w * 32 + 16 + r) * 40 + q * 8];
        bf16x8 b0 = *(const bf16x8*)&Xb[(nh * 64 + 0  + r) * 40 + q * 8];
        bf16x8 b1 = *(const bf16x8*)&Xb[(nh * 64 + 16 + r) * 40 + q * 8];
        bf16x8 b2 = *(const bf16x8*)&Xb[(nh * 64 + 32 + r) * 40 + q * 8];
        bf16x8 b3 = *(const bf16x8*)&Xb[(nh * 64 + 48 + r) * 40 + q * 8];
        acc[0][0] = MFMA(a0, b0, acc[0][0]);
        acc[0][1] = MFMA(a0, b1, acc[0][1]);
        acc[0][2] = MFMA(a0, b2, acc[0][2]);
        acc[0][3] = MFMA(a0, b3, acc[0][3]);
        acc[1][0] = MFMA(a1, b0, acc[1][0]);
        acc[1][1] = MFMA(a1, b1, acc[1][1]);
        acc[1][2] = MFMA(a1, b2, acc[1][2]);
        acc[1][3] = MFMA(a1, b3, acc[1][3]);
    }
    __syncthreads();    // all MFMA reads done; reuse smf as Gl
    #pragma unroll
    for (int mi = 0; mi < 2; ++mi)
        #pragma unroll
        for (int ni = 0; ni < 4; ++ni) {
            int cb = w * 32 + mi * 16 + q * 4;
            int dl = ni * 16 + r;
            #pragma unroll
            for (int j = 0; j < 4; ++j) Gl[(cb + j) * 66 + dl] = acc[mi][ni][j];
        }
    __syncthreads();
    {
        int dl = t & 63, cq = t >> 6;
        float p = 0.f;
        #pragma unroll 8
        for (int i = 0; i < 32; ++i) {
            int c = cq * 32 + i;
            p += WsumT[(size_t)c * C_ + nh * 64 + dl] * Gl[c * 66 + dl];
        }
        red[t] = p;
    }
    __syncthreads();
    if (t < 64)
        A1row[(size_t)bf * C_ + nh * 64 + t] = red[t] + red[t + 64] + red[t + 128] + red[t + 192];
    if (nh == 0) {
        float vv0 = a2p0, vv1 = a2p1, vv2 = a2p2, vv3 = a2p3;
        #pragma unroll
        for (int it = 0; it < 4; ++it) {
            float v2 = (it == 0) ? vv0 : (it == 1) ? vv1 : (it == 2) ? vv2 : vv3;
            v2 += __shfl_xor(v2, 1);
            v2 += __shfl_xor(v2, 2);
            v2 += __shfl_xor(v2, 4);
            if ((t & 7) == 0) A2row[(size_t)bf * C_ + it * 32 + (t >> 3)] = v2;
        }
    }
}

// ---------------- Meff = (Wn . diag(A2)) * Wdiff (bf16 MFMA); c0 = Wn*(A1+A2.*bd) ----------------
__global__ __launch_bounds__(256) void k_meff(
    const float* __restrict__ A1row, const float* __restrict__ A2row,
    const float* __restrict__ Wn, const float* __restrict__ WnT,
    const ushort* __restrict__ WdT_bf, const float* __restrict__ bd,
    ushort* __restrict__ Meff_bf, float* __restrict__ c0all)
{
    __shared__ ushort Zl[16384];   // swizzled Z[o][k]; reused for output repack
    __shared__ ushort Wl[16384];   // swizzled WdT[c][k]
    __shared__ float A2l[C_], El[C_];
    int bf = blockIdx.x, t = threadIdx.x;
    if (t < C_) {
        float a2 = A2row[(size_t)bf * C_ + t];
        A2l[t] = a2;
        El[t] = A1row[(size_t)bf * C_ + t] + a2 * bd[t];
    }
    __syncthreads();
    #pragma unroll
    for (int it = 0; it < 8; ++it) {
        int idx = it * 256 + t;                     // 0..2047
        int rowi = idx >> 4, ch = idx & 15;
        bf16x8 wv = *(const bf16x8*)&WdT_bf[(size_t)rowi * C_ + ch * 8];
        *(bf16x8*)((char*)Wl + SWZ(rowi * 256 + ch * 16)) = wv;
        const float4 w0 = *(const float4*)&Wn[(size_t)rowi * C_ + ch * 8];
        const float4 w1 = *(const float4*)&Wn[(size_t)rowi * C_ + ch * 8 + 4];
        bf16x8 z;
        z[0] = (short)f2bf(w0.x * A2l[ch * 8 + 0]);
        z[1] = (short)f2bf(w0.y * A2l[ch * 8 + 1]);
        z[2] = (short)f2bf(w0.z * A2l[ch * 8 + 2]);
        z[3] = (short)f2bf(w0.w * A2l[ch * 8 + 3]);
        z[4] = (short)f2bf(w1.x * A2l[ch * 8 + 4]);
        z[5] = (short)f2bf(w1.y * A2l[ch * 8 + 5]);
        z[6] = (short)f2bf(w1.z * A2l[ch * 8 + 6]);
        z[7] = (short)f2bf(w1.w * A2l[ch * 8 + 7]);
        *(bf16x8*)((char*)Zl + SWZ(rowi * 256 + ch * 16)) = z;
    }
    __syncthreads();
    int l = t & 63, w = t >> 6, r = l & 15, q = l >> 4;
    f32x4 acc[2][8];
    #pragma unroll
    for (int mi = 0; mi < 2; ++mi)
        #pragma unroll
        for (int ni = 0; ni < 8; ++ni) acc[mi][ni] = (f32x4){0.f, 0.f, 0.f, 0.f};
    #pragma unroll
    for (int ks = 0; ks < 4; ++ks) {
        int ko = ks * 64 + q * 16;
        bf16x8 a0 = *(const bf16x8*)((char*)Zl + SWZ((w * 32 + r) * 256 + ko));
        bf16x8 a1 = *(const bf16x8*)((char*)Zl + SWZ((w * 32 + 16 + r) * 256 + ko));
        #pragma unroll
        for (int ni = 0; ni < 8; ++ni) {
            bf16x8 bb = *(const bf16x8*)((char*)Wl + SWZ((ni * 16 + r) * 256 + ko));
            acc[0][ni] = MFMA(a0, bb, acc[0][ni]);
            acc[1][ni] = MFMA(a1, bb, acc[1][ni]);
        }
    }
    __syncthreads();   // done reading Zl; reuse as linear repack buffer
    #pragma unroll
    for (int mi = 0; mi < 2; ++mi)
        #pragma unroll
        for (int ni = 0; ni < 8; ++ni) {
            int o = w * 32 + mi * 16 + q * 4;
            int c = ni * 16 + r;
            #pragma unroll
            for (int j = 0; j < 4; ++j) Zl[(o + j) * C_ + c] = f2bf(acc[mi][ni][j]);
        }
    __syncthreads();
    #pragma unroll
    for (int it = 0; it < 8; ++it) {
        int idx = it * 256 + t;
        int rowi = idx >> 4, ch = idx & 15;
        *(bf16x8*)&Meff_bf[(size_t)bf * 16384 + rowi * C_ + ch * 8] =
            *(const bf16x8*)&Zl[rowi * C_ + ch * 8];
    }
    if (t < C_) {
        float s = 0.f;
        for (int c = 0; c < C_; ++c) s += WnT[(size_t)c * C_ + t] * El[c];
        c0all[(size_t)bf * C_ + t] = s;
    }
}

// ---------------- final: out = relu((Meff*X + c0)/deg + bn), MFMA, fused store ----------------
__global__ __launch_bounds__(256) void k_final(
    const float* __restrict__ infos, const ushort* __restrict__ Meff_bf,
    const float* __restrict__ c0all, const float* __restrict__ deg,
    const int* __restrict__ cnt, const int* __restrict__ list,
    const float* __restrict__ Wsum, const float* __restrict__ Wdiff,
    const float* __restrict__ Wn, const float* __restrict__ bd, const float* __restrict__ bn,
    float* __restrict__ out)
{
    __shared__ ushort Ml[16384];    // swizzled Meff[o][c], 32KB
    __shared__ ushort Xv[8192];     // swizzled X^T[vloc][c], 16KB
    __shared__ float Xu[C_], Xvf[C_], NC[C_], corrv[C_];
    int bf = blockIdx.x, vb = blockIdx.y, t = threadIdx.x;
    int b = bf >> 4, f = bf & 15;
    int g = (f == 0) ? 0 : ((f <= 11) ? 1 : 2);
    int bg = b * 3 + g;
    int v0 = vb * 64;
    const float* Xg = infos + ((size_t)b * C_ * F_ + f) * N_;

    #pragma unroll
    for (int it = 0; it < 8; ++it) {
        int idx = it * 256 + t;
        int o = idx >> 4, ch = idx & 15;
        bf16x8 mv = *(const bf16x8*)&Meff_bf[(size_t)bf * 16384 + o * C_ + ch * 8];
        *(bf16x8*)((char*)Ml + SWZ(o * 256 + ch * 16)) = mv;
    }
    #pragma unroll
    for (int it = 0; it < 4; ++it) {
        int idx = it * 256 + t;                     // 0..1023
        int cp = idx >> 4, vq = idx & 15;
        const float* r0 = Xg + (size_t)(2 * cp) * (F_ * N_) + v0 + vq * 4;
        const float* r1 = r0 + (F_ * N_);
        float4 x0 = *(const float4*)r0;
        float4 x1 = *(const float4*)r1;
        float e0[4] = {x0.x, x0.y, x0.z, x0.w};
        float e1[4] = {x1.x, x1.y, x1.z, x1.w};
        #pragma unroll
        for (int j = 0; j < 4; ++j) {
            int vloc = vq * 4 + j;
            unsigned word = (unsigned)f2bf(e0[j]) | ((unsigned)f2bf(e1[j]) << 16);
            *(unsigned*)((char*)Xv + SWZ(vloc * 256 + cp * 4)) = word;
        }
    }
    __syncthreads();

    int l = t & 63, w = t >> 6, r = l & 15, q = l >> 4;
    f32x4 acc[2][4];
    #pragma unroll
    for (int mi = 0; mi < 2; ++mi)
        #pragma unroll
        for (int ni = 0; ni < 4; ++ni) acc[mi][ni] = (f32x4){0.f, 0.f, 0.f, 0.f};
    #pragma unroll
    for (int ks = 0; ks < 4; ++ks) {
        int ko = ks * 64 + q * 16;
        bf16x8 a0 = *(const bf16x8*)((char*)Ml + SWZ((w * 32 + r) * 256 + ko));
        bf16x8 a1 = *(const bf16x8*)((char*)Ml + SWZ((w * 32 + 16 + r) * 256 + ko));
        #pragma unroll
        for (int nt = 0; nt < 4; ++nt) {
            bf16x8 bb = *(const bf16x8*)((char*)Xv + SWZ((nt * 16 + r) * 256 + ko));
            acc[0][nt] = MFMA(a0, bb, acc[0][nt]);
            acc[1][nt] = MFMA(a1, bb, acc[1][nt]);
        }
    }

    // ---- rare zero-edge corrections ----
    int nz = cnt[bg];
    for (int e = 0; e < nz; ++e) {
        int p = list[(size_t)bg * CAP_ + e];
        int u = p >> 9, v = p & 511;
        if ((v >> 6) != vb) continue;
        int vloc = v - v0;
        __syncthreads();
        if (t < C_) {
            Xu[t]  = Xg[(size_t)t * (F_ * N_) + u];
            Xvf[t] = Xg[(size_t)t * (F_ * N_) + v];
        }
        __syncthreads();
        if (t < C_) {
            float s = 0.f, dv = 0.f;
            const float* wsr = Wsum + (size_t)t * C_;
            const float* wdr = Wdiff + (size_t)t * C_;
            for (int c = 0; c < C_; ++c) { s += wsr[c] * Xu[c]; dv += wdr[c] * Xvf[c]; }
            NC[t] = Xu[t] * (s + dv + bd[t]);
        }
        __syncthreads();
        if (t < C_) {
            float s = 0.f;
            const float* wnr = Wn + (size_t)t * C_;
            for (int c = 0; c < C_; ++c) s += wnr[c] * NC[c];
            corrv[t] = s;
        }
        __syncthreads();
        int ntv = vloc >> 4;
        #pragma unroll
        for (int nt = 0; nt < 4; ++nt) {
            if (nt == ntv && r == (vloc & 15)) {
                #pragma unroll
                for (int mi = 0; mi < 2; ++mi)
                    #pragma unroll
                    for (int j = 0; j < 4; ++j)
                        acc[mi][nt][j] -= corrv[w * 32 + mi * 16 + q * 4 + j];
            }
        }
    }

    // ---- epilogue ----
    float c0v[2][4], bnv[2][4];
    #pragma unroll
    for (int mi = 0; mi < 2; ++mi)
        #pragma unroll
        for (int j = 0; j < 4; ++j) {
            int o = w * 32 + mi * 16 + q * 4 + j;
            c0v[mi][j] = c0all[(size_t)bf * C_ + o];
            bnv[mi][j] = bn[o];
        }
    #pragma unroll
    for (int nt = 0; nt < 4; ++nt) {
        int v = v0 + nt * 16 + r;
        float dg = fmaxf(deg[(size_t)bg * N_ + v], 1.f);
        #pragma unroll
        for (int mi = 0; mi < 2; ++mi) {
            #pragma unroll
            for (int j = 0; j < 4; ++j) {
                int o = w * 32 + mi * 16 + q * 4 + j;
                float val = fmaxf((acc[mi][nt][j] + c0v[mi][j]) / dg + bnv[mi][j], 0.f);
                out[((size_t)b * C_ + o) * (F_ * N_) + (size_t)f * N_ + v] = val;
            }
        }
    }
}

extern "C" void kernel_launch(void* const* d_in, const int* in_sizes, int n_in,
                              void* d_out, int out_size, void* d_ws, size_t ws_size,
                              hipStream_t stream)
{
    const float* Y     = (const float*)d_in[0];
    const float* infos = (const float*)d_in[1];
    const float* Wd    = (const float*)d_in[2];
    const float* bd    = (const float*)d_in[3];
    const float* Wn    = (const float*)d_in[4];
    const float* bn    = (const float*)d_in[5];
    float* out = (float*)d_out;
    float* ws  = (float*)d_ws;

    float*  deg     = ws;                              // 12288
    int*    cnt     = (int*)(ws + 12288);              // 32 ints
    float*  A1row   = ws + 12320;                      // 16384
    float*  A2row   = A1row + 16384;
    float*  Wsum    = A2row + 16384;
    float*  Wdiff   = Wsum + 16384;
    float*  WsumT   = Wdiff + 16384;
    float*  WnT     = WsumT + 16384;
    float*  c0all   = WnT + 16384;
    ushort* WdT_bf  = (ushort*)(c0all + 16384);        // 16384 ushort
    ushort* Meff_bf = (ushort*)(c0all + 16384 + 8192); // 2097152 ushort
    int*    list    = (int*)(c0all + 16384 + 8192 + 1048576);

    hipMemsetAsync(cnt, 0, 32 * sizeof(int), stream);
    k_wprep<<<64, 256, 0, stream>>>(Wd, Wn, Wsum, Wdiff, WsumT, WdT_bf, WnT);
    k_deg<<<dim3(24, 16), 256, 0, stream>>>(Y, deg, cnt, list);
    k_gram<<<dim3(B_ * F_, 2), 256, 0, stream>>>(infos, WsumT, A1row, A2row);
    k_meff<<<B_ * F_, 256, 0, stream>>>(A1row, A2row, Wn, WnT, WdT_bf, bd, Meff_bf, c0all);
    k_final<<<dim3(B_ * F_, 8), 256, 0, stream>>>(infos, Meff_bf, c0all, deg, cnt, list,
                                                  Wsum, Wdiff, Wn, bd, bn, out);
}

// Round 5
// 284.066 us; speedup vs baseline: 5.8447x; 1.0543x over previous
//
#include <hip/hip_runtime.h>
#include <hip/hip_bf16.h>

#define B_ 8
#define C_ 128
#define F_ 16
#define N_ 512
#define CAP_ (N_ * N_)

typedef __attribute__((ext_vector_type(8))) short bf16x8;
typedef __attribute__((ext_vector_type(4))) float f32x4;

#define MFMA(a, b, c) __builtin_amdgcn_mfma_f32_16x16x32_bf16((a), (b), (c), 0, 0, 0)
#define SWZ(x) ((x) ^ ((((x) >> 8) & 7) << 4))

__device__ __forceinline__ ushort f2bf(float x) {
    union { __hip_bfloat16 h; ushort u; } cv;
    cv.h = __float2bfloat16(x);
    return cv.u;
}

// ---------------- fused: degree/zero-list (y<8) + weight prep (y==8) ----------------
__global__ __launch_bounds__(256) void k_prep(
    const float* __restrict__ Y, const float* __restrict__ Wd, const float* __restrict__ Wn,
    float* __restrict__ deg, int* __restrict__ cnt, int* __restrict__ list,
    float* __restrict__ Wsum, float* __restrict__ Wdiff, float* __restrict__ WsumT,
    ushort* __restrict__ WdT_bf, float* __restrict__ WnT)
{
    int t = threadIdx.x;
    if (blockIdx.y == 8) {
        // weight prep: 24 blocks, grid-stride over 16384 items
        for (int i = blockIdx.x * 256 + t; i < C_ * C_; i += 24 * 256) {
            int d = i >> 7, c = i & 127;
            const float* row = Wd + (size_t)d * (3 * C_);
            float w1 = row[c], w2 = row[C_ + c], w3 = row[2 * C_ + c];
            float ws = w1 + w3, wdf = w2 - w3;
            Wsum[i] = ws;
            Wdiff[i] = wdf;
            WsumT[(size_t)c * C_ + d] = ws;
            WdT_bf[(size_t)c * C_ + d] = f2bf(wdf);
            WnT[i] = Wn[(size_t)(i & 127) * C_ + (i >> 7)];
        }
        return;
    }
    __shared__ float red0[256], red1[256];
    int bg = blockIdx.x, vc = blockIdx.y;
    int b = bg / 3, g = bg % 3;
    int p = t & 31, q = t >> 5;            // vpair p, u-segment q (64 rows each)
    int v = vc * 64 + p * 2;
    const float* Yp = Y + ((size_t)b * F_ + g) * N_ * N_;
    float d0 = 0.f, d1 = 0.f;
    #pragma unroll 4
    for (int i = 0; i < 64; ++i) {
        int u = q * 64 + i;
        float2 a = *(const float2*)(Yp + (size_t)u * N_ + v);
        if (a.x == 0.f) {
            int idx = atomicAdd(&cnt[bg], 1);
            list[(size_t)bg * CAP_ + idx] = (u << 9) | v;
        } else d0 += 1.f;
        if (a.y == 0.f) {
            int idx = atomicAdd(&cnt[bg], 1);
            list[(size_t)bg * CAP_ + idx] = (u << 9) | (v + 1);
        } else d1 += 1.f;
    }
    red0[t] = d0;
    red1[t] = d1;
    __syncthreads();
    if (t < 32) {
        float s0 = 0.f, s1 = 0.f;
        #pragma unroll
        for (int qq = 0; qq < 8; ++qq) { s0 += red0[qq * 32 + t]; s1 += red1[qq * 32 + t]; }
        deg[(size_t)bg * N_ + vc * 64 + t * 2]     = s0;
        deg[(size_t)bg * N_ + vc * 64 + t * 2 + 1] = s1;
    }
}

// ---------------- Gram: G=X^T X via MFMA (pipelined); A1=diag(Wsum*G); A2=colsum(X) ----------------
__global__ __launch_bounds__(256) void k_gram(
    const float* __restrict__ infos, const float* __restrict__ WsumT,
    float* __restrict__ A1row, float* __restrict__ A2row)
{
    __shared__ float smf[8448];           // union: Xs dbuf (2x128x40 shorts) / Gl 128x66 f32
    __shared__ float red[256];
    short* Xs = (short*)smf;
    float* Gl = smf;
    int bf = blockIdx.x, nh = blockIdx.y, t = threadIdx.x;
    int b = bf >> 4, f = bf & 15;
    const float* Xg = infos + ((size_t)b * C_ * F_ + f) * N_;

    float a2p0 = 0.f, a2p1 = 0.f, a2p2 = 0.f, a2p3 = 0.f;
    float4 pre0, pre1, pre2, pre3;
    int sc = t >> 3, suq = t & 7;         // staging: thread covers c = it*32+sc, u-quad suq

    auto LOADREG = [&](int ks) {
        int u0 = ks * 32;
        const float* pbase = Xg + (size_t)sc * (F_ * N_) + u0 + suq * 4;
        pre0 = *(const float4*)(pbase);
        pre1 = *(const float4*)(pbase + 32 * (F_ * N_));
        pre2 = *(const float4*)(pbase + 64 * (F_ * N_));
        pre3 = *(const float4*)(pbase + 96 * (F_ * N_));
    };
    auto WRITELDS = [&](int buf) {
        short* dst = &Xs[buf * 5120 + sc * 40 + suq * 4];
        float4 xs[4] = {pre0, pre1, pre2, pre3};
        #pragma unroll
        for (int it = 0; it < 4; ++it) {
            float4 x = xs[it];
            float s4 = x.x + x.y + x.z + x.w;
            if (it == 0) a2p0 += s4; else if (it == 1) a2p1 += s4;
            else if (it == 2) a2p2 += s4; else a2p3 += s4;
            short4 h;
            h.x = (short)f2bf(x.x); h.y = (short)f2bf(x.y);
            h.z = (short)f2bf(x.z); h.w = (short)f2bf(x.w);
            *(short4*)(dst + it * 32 * 40) = h;
        }
    };

    int l = t & 63, w = t >> 6;
    int r = l & 15, q = l >> 4;
    f32x4 acc[2][4];
    #pragma unroll
    for (int mi = 0; mi < 2; ++mi)
        #pragma unroll
        for (int ni = 0; ni < 4; ++ni) acc[mi][ni] = (f32x4){0.f, 0.f, 0.f, 0.f};

    LOADREG(0);
    WRITELDS(0);
    for (int ks = 0; ks < 16; ++ks) {
        __syncthreads();
        if (ks < 15) LOADREG(ks + 1);     // global loads in flight during MFMA
        const short* Xb = &Xs[(ks & 1) * 5120];
        bf16x8 a0 = *(const bf16x8*)&Xb[(w * 32 + r) * 40 + q * 8];
        bf16x8 a1 = *(const bf16x8*)&Xb[(w * 32 + 16 + r) * 40 + q * 8];
        bf16x8 b0 = *(const bf16x8*)&Xb[(nh * 64 + 0  + r) * 40 + q * 8];
        bf16x8 b1 = *(const bf16x8*)&Xb[(nh * 64 + 16 + r) * 40 + q * 8];
        bf16x8 b2 = *(const bf16x8*)&Xb[(nh * 64 + 32 + r) * 40 + q * 8];
        bf16x8 b3 = *(const bf16x8*)&Xb[(nh * 64 + 48 + r) * 40 + q * 8];
        acc[0][0] = MFMA(a0, b0, acc[0][0]);
        acc[0][1] = MFMA(a0, b1, acc[0][1]);
        acc[0][2] = MFMA(a0, b2, acc[0][2]);
        acc[0][3] = MFMA(a0, b3, acc[0][3]);
        acc[1][0] = MFMA(a1, b0, acc[1][0]);
        acc[1][1] = MFMA(a1, b1, acc[1][1]);
        acc[1][2] = MFMA(a1, b2, acc[1][2]);
        acc[1][3] = MFMA(a1, b3, acc[1][3]);
        if (ks < 15) WRITELDS((ks + 1) & 1);
    }
    __syncthreads();    // all MFMA reads done; reuse smf as Gl
    #pragma unroll
    for (int mi = 0; mi < 2; ++mi)
        #pragma unroll
        for (int ni = 0; ni < 4; ++ni) {
            int cb = w * 32 + mi * 16 + q * 4;
            int dl = ni * 16 + r;
            #pragma unroll
            for (int j = 0; j < 4; ++j) Gl[(cb + j) * 66 + dl] = acc[mi][ni][j];
        }
    __syncthreads();
    {
        int dl = t & 63, cq = t >> 6;
        float pacc = 0.f;
        #pragma unroll 8
        for (int i = 0; i < 32; ++i) {
            int c = cq * 32 + i;
            pacc += WsumT[(size_t)c * C_ + nh * 64 + dl] * Gl[c * 66 + dl];
        }
        red[t] = pacc;
    }
    __syncthreads();
    if (t < 64)
        A1row[(size_t)bf * C_ + nh * 64 + t] = red[t] + red[t + 64] + red[t + 128] + red[t + 192];
    if (nh == 0) {
        #pragma unroll
        for (int it = 0; it < 4; ++it) {
            float v2 = (it == 0) ? a2p0 : (it == 1) ? a2p1 : (it == 2) ? a2p2 : a2p3;
            v2 += __shfl_xor(v2, 1);
            v2 += __shfl_xor(v2, 2);
            v2 += __shfl_xor(v2, 4);
            if ((t & 7) == 0) A2row[(size_t)bf * C_ + it * 32 + (t >> 3)] = v2;
        }
    }
}

// ---------------- Meff = (Wn . diag(A2)) * Wdiff (bf16 MFMA); c0 = Wn*(A1+A2.*bd) ----------------
__global__ __launch_bounds__(256) void k_meff(
    const float* __restrict__ A1row, const float* __restrict__ A2row,
    const float* __restrict__ Wn, const float* __restrict__ WnT,
    const ushort* __restrict__ WdT_bf, const float* __restrict__ bd,
    ushort* __restrict__ Meff_bf, float* __restrict__ c0all)
{
    __shared__ ushort Zl[16384];
    __shared__ ushort Wl[16384];
    __shared__ float A2l[C_], El[C_];
    int bf = blockIdx.x, t = threadIdx.x;
    if (t < C_) {
        float a2 = A2row[(size_t)bf * C_ + t];
        A2l[t] = a2;
        El[t] = A1row[(size_t)bf * C_ + t] + a2 * bd[t];
    }
    __syncthreads();
    #pragma unroll
    for (int it = 0; it < 8; ++it) {
        int idx = it * 256 + t;
        int rowi = idx >> 4, ch = idx & 15;
        bf16x8 wv = *(const bf16x8*)&WdT_bf[(size_t)rowi * C_ + ch * 8];
        *(bf16x8*)((char*)Wl + SWZ(rowi * 256 + ch * 16)) = wv;
        const float4 w0 = *(const float4*)&Wn[(size_t)rowi * C_ + ch * 8];
        const float4 w1 = *(const float4*)&Wn[(size_t)rowi * C_ + ch * 8 + 4];
        bf16x8 z;
        z[0] = (short)f2bf(w0.x * A2l[ch * 8 + 0]);
        z[1] = (short)f2bf(w0.y * A2l[ch * 8 + 1]);
        z[2] = (short)f2bf(w0.z * A2l[ch * 8 + 2]);
        z[3] = (short)f2bf(w0.w * A2l[ch * 8 + 3]);
        z[4] = (short)f2bf(w1.x * A2l[ch * 8 + 4]);
        z[5] = (short)f2bf(w1.y * A2l[ch * 8 + 5]);
        z[6] = (short)f2bf(w1.z * A2l[ch * 8 + 6]);
        z[7] = (short)f2bf(w1.w * A2l[ch * 8 + 7]);
        *(bf16x8*)((char*)Zl + SWZ(rowi * 256 + ch * 16)) = z;
    }
    __syncthreads();
    int l = t & 63, w = t >> 6, r = l & 15, q = l >> 4;
    f32x4 acc[2][8];
    #pragma unroll
    for (int mi = 0; mi < 2; ++mi)
        #pragma unroll
        for (int ni = 0; ni < 8; ++ni) acc[mi][ni] = (f32x4){0.f, 0.f, 0.f, 0.f};
    #pragma unroll
    for (int ks = 0; ks < 4; ++ks) {
        int ko = ks * 64 + q * 16;
        bf16x8 a0 = *(const bf16x8*)((char*)Zl + SWZ((w * 32 + r) * 256 + ko));
        bf16x8 a1 = *(const bf16x8*)((char*)Zl + SWZ((w * 32 + 16 + r) * 256 + ko));
        #pragma unroll
        for (int ni = 0; ni < 8; ++ni) {
            bf16x8 bb = *(const bf16x8*)((char*)Wl + SWZ((ni * 16 + r) * 256 + ko));
            acc[0][ni] = MFMA(a0, bb, acc[0][ni]);
            acc[1][ni] = MFMA(a1, bb, acc[1][ni]);
        }
    }
    __syncthreads();
    #pragma unroll
    for (int mi = 0; mi < 2; ++mi)
        #pragma unroll
        for (int ni = 0; ni < 8; ++ni) {
            int o = w * 32 + mi * 16 + q * 4;
            int c = ni * 16 + r;
            #pragma unroll
            for (int j = 0; j < 4; ++j) Zl[(o + j) * C_ + c] = f2bf(acc[mi][ni][j]);
        }
    __syncthreads();
    #pragma unroll
    for (int it = 0; it < 8; ++it) {
        int idx = it * 256 + t;
        int rowi = idx >> 4, ch = idx & 15;
        *(bf16x8*)&Meff_bf[(size_t)bf * 16384 + rowi * C_ + ch * 8] =
            *(const bf16x8*)&Zl[rowi * C_ + ch * 8];
    }
    if (t < C_) {
        float s = 0.f;
        for (int c = 0; c < C_; ++c) s += WnT[(size_t)c * C_ + t] * El[c];
        c0all[(size_t)bf * C_ + t] = s;
    }
}

// ---------------- final: out = relu((Meff*X + c0)/deg + bn), MFMA, vectorized store ----------------
__global__ __launch_bounds__(256) void k_final(
    const float* __restrict__ infos, const ushort* __restrict__ Meff_bf,
    const float* __restrict__ c0all, const float* __restrict__ deg,
    const int* __restrict__ cnt, const int* __restrict__ list,
    const float* __restrict__ Wsum, const float* __restrict__ Wdiff,
    const float* __restrict__ Wn, const float* __restrict__ bd, const float* __restrict__ bn,
    float* __restrict__ out)
{
    __shared__ char arena[49152];           // Ml 32KB + Xv 16KB; reused as Sl 128x66 f32
    ushort* Ml = (ushort*)arena;
    ushort* Xv = (ushort*)(arena + 32768);
    float*  Sl = (float*)arena;
    __shared__ float Xu[C_], Xvf[C_], NC[C_], corrv[C_];
    int bf = blockIdx.x, vb = blockIdx.y, t = threadIdx.x;
    int b = bf >> 4, f = bf & 15;
    int g = (f == 0) ? 0 : ((f <= 11) ? 1 : 2);
    int bg = b * 3 + g;
    int v0 = vb * 64;
    const float* Xg = infos + ((size_t)b * C_ * F_ + f) * N_;

    #pragma unroll
    for (int it = 0; it < 8; ++it) {
        int idx = it * 256 + t;
        int o = idx >> 4, ch = idx & 15;
        bf16x8 mv = *(const bf16x8*)&Meff_bf[(size_t)bf * 16384 + o * C_ + ch * 8];
        *(bf16x8*)((char*)Ml + SWZ(o * 256 + ch * 16)) = mv;
    }
    #pragma unroll
    for (int it = 0; it < 4; ++it) {
        int idx = it * 256 + t;
        int cp = idx >> 4, vq = idx & 15;
        const float* r0 = Xg + (size_t)(2 * cp) * (F_ * N_) + v0 + vq * 4;
        const float* r1 = r0 + (F_ * N_);
        float4 x0 = *(const float4*)r0;
        float4 x1 = *(const float4*)r1;
        float e0[4] = {x0.x, x0.y, x0.z, x0.w};
        float e1[4] = {x1.x, x1.y, x1.z, x1.w};
        #pragma unroll
        for (int j = 0; j < 4; ++j) {
            int vloc = vq * 4 + j;
            unsigned word = (unsigned)f2bf(e0[j]) | ((unsigned)f2bf(e1[j]) << 16);
            *(unsigned*)((char*)Xv + SWZ(vloc * 256 + cp * 4)) = word;
        }
    }
    __syncthreads();

    int l = t & 63, w = t >> 6, r = l & 15, q = l >> 4;
    f32x4 acc[2][4];
    #pragma unroll
    for (int mi = 0; mi < 2; ++mi)
        #pragma unroll
        for (int ni = 0; ni < 4; ++ni) acc[mi][ni] = (f32x4){0.f, 0.f, 0.f, 0.f};
    #pragma unroll
    for (int ks = 0; ks < 4; ++ks) {
        int ko = ks * 64 + q * 16;
        bf16x8 a0 = *(const bf16x8*)((char*)Ml + SWZ((w * 32 + r) * 256 + ko));
        bf16x8 a1 = *(const bf16x8*)((char*)Ml + SWZ((w * 32 + 16 + r) * 256 + ko));
        #pragma unroll
        for (int nt = 0; nt < 4; ++nt) {
            bf16x8 bb = *(const bf16x8*)((char*)Xv + SWZ((nt * 16 + r) * 256 + ko));
            acc[0][nt] = MFMA(a0, bb, acc[0][nt]);
            acc[1][nt] = MFMA(a1, bb, acc[1][nt]);
        }
    }

    // ---- rare zero-edge corrections ----
    int nz = cnt[bg];
    for (int e = 0; e < nz; ++e) {
        int p = list[(size_t)bg * CAP_ + e];
        int u = p >> 9, v = p & 511;
        if ((v >> 6) != vb) continue;
        int vloc = v - v0;
        __syncthreads();
        if (t < C_) {
            Xu[t]  = Xg[(size_t)t * (F_ * N_) + u];
            Xvf[t] = Xg[(size_t)t * (F_ * N_) + v];
        }
        __syncthreads();
        if (t < C_) {
            float s = 0.f, dv = 0.f;
            const float* wsr = Wsum + (size_t)t * C_;
            const float* wdr = Wdiff + (size_t)t * C_;
            for (int c = 0; c < C_; ++c) { s += wsr[c] * Xu[c]; dv += wdr[c] * Xvf[c]; }
            NC[t] = Xu[t] * (s + dv + bd[t]);
        }
        __syncthreads();
        if (t < C_) {
            float s = 0.f;
            const float* wnr = Wn + (size_t)t * C_;
            for (int c = 0; c < C_; ++c) s += wnr[c] * NC[c];
            corrv[t] = s;
        }
        __syncthreads();
        int ntv = vloc >> 4;
        #pragma unroll
        for (int nt = 0; nt < 4; ++nt) {
            if (nt == ntv && r == (vloc & 15)) {
                #pragma unroll
                for (int mi = 0; mi < 2; ++mi)
                    #pragma unroll
                    for (int j = 0; j < 4; ++j)
                        acc[mi][nt][j] -= corrv[w * 32 + mi * 16 + q * 4 + j];
            }
        }
    }

    // ---- epilogue: compute values, bounce through LDS, vectorized store ----
    float c0v[2][4], bnv[2][4];
    #pragma unroll
    for (int mi = 0; mi < 2; ++mi)
        #pragma unroll
        for (int j = 0; j < 4; ++j) {
            int o = w * 32 + mi * 16 + q * 4 + j;
            c0v[mi][j] = c0all[(size_t)bf * C_ + o];
            bnv[mi][j] = bn[o];
        }
    __syncthreads();   // Ml/Xv reads complete; arena becomes Sl
    #pragma unroll
    for (int nt = 0; nt < 4; ++nt) {
        int v = v0 + nt * 16 + r;
        float dg = fmaxf(deg[(size_t)bg * N_ + v], 1.f);
        #pragma unroll
        for (int mi = 0; mi < 2; ++mi) {
            int o = w * 32 + mi * 16 + q * 4;
            #pragma unroll
            for (int j = 0; j < 4; ++j) {
                float val = fmaxf((acc[mi][nt][j] + c0v[mi][j]) / dg + bnv[mi][j], 0.f);
                Sl[(o + j) * 66 + nt * 16 + r] = val;
            }
        }
    }
    __syncthreads();
    {
        int o = t >> 1, half = t & 1;
        float* src = &Sl[o * 66 + half * 32];
        float* dst = &out[((size_t)b * C_ + o) * (F_ * N_) + (size_t)f * N_ + v0 + half * 32];
        #pragma unroll
        for (int j = 0; j < 8; ++j)
            *(float4*)(dst + j * 4) = *(const float4*)(src + j * 4);
    }
}

extern "C" void kernel_launch(void* const* d_in, const int* in_sizes, int n_in,
                              void* d_out, int out_size, void* d_ws, size_t ws_size,
                              hipStream_t stream)
{
    const float* Y     = (const float*)d_in[0];
    const float* infos = (const float*)d_in[1];
    const float* Wd    = (const float*)d_in[2];
    const float* bd    = (const float*)d_in[3];
    const float* Wn    = (const float*)d_in[4];
    const float* bn    = (const float*)d_in[5];
    float* out = (float*)d_out;
    float* ws  = (float*)d_ws;

    float*  deg     = ws;                              // 12288
    int*    cnt     = (int*)(ws + 12288);              // 32 ints
    float*  A1row   = ws + 12320;                      // 16384
    float*  A2row   = A1row + 16384;
    float*  Wsum    = A2row + 16384;
    float*  Wdiff   = Wsum + 16384;
    float*  WsumT   = Wdiff + 16384;
    float*  WnT     = WsumT + 16384;
    float*  c0all   = WnT + 16384;
    ushort* WdT_bf  = (ushort*)(c0all + 16384);        // 16384 ushort
    ushort* Meff_bf = (ushort*)(c0all + 16384 + 8192); // 2097152 ushort
    int*    list    = (int*)(c0all + 16384 + 8192 + 1048576);

    hipMemsetAsync(cnt, 0, 32 * sizeof(int), stream);
    k_prep<<<dim3(24, 9), 256, 0, stream>>>(Y, Wd, Wn, deg, cnt, list,
                                            Wsum, Wdiff, WsumT, WdT_bf, WnT);
    k_gram<<<dim3(B_ * F_, 2), 256, 0, stream>>>(infos, WsumT, A1row, A2row);
    k_meff<<<B_ * F_, 256, 0, stream>>>(A1row, A2row, Wn, WnT, WdT_bf, bd, Meff_bf, c0all);
    k_final<<<dim3(B_ * F_, 8), 256, 0, stream>>>(infos, Meff_bf, c0all, deg, cnt, list,
                                                  Wsum, Wdiff, Wn, bd, bn, out);
}